// Round 2
// baseline (596.808 us; speedup 1.0000x reference)
//
#include <hip/hip_runtime.h>
#include <stdint.h>

typedef __attribute__((ext_vector_type(8))) short short8;
typedef __attribute__((ext_vector_type(4))) float f32x4;

#define T_STEPS 256
#define BATCH   128
#define HID     512

static __device__ inline unsigned short f2bf(float f) {
    unsigned int u = __float_as_uint(f);
    unsigned int r = u + 0x7FFFu + ((u >> 16) & 1u);
    return (unsigned short)(r >> 16);
}

// ---------------- kernel 0: cur1s[t][btile][thr][32] = (xn@W1^T + b1)/thr1 ----------------
__global__ __launch_bounds__(256) void k_cur1(const float* __restrict__ batch,
    const float* __restrict__ W1, const float* __restrict__ b1,
    const float* __restrict__ thr1, const float* __restrict__ inp_min_p,
    const float* __restrict__ inp_max_p, float* __restrict__ cur1s)
{
    int gid   = blockIdx.x * 256 + threadIdx.x;   // 4,194,304 total
    int i4    = gid & 7;
    int thr   = (gid >> 3) & 255;
    int btile = (gid >> 11) & 7;
    int tt    = gid >> 14;
    int b_loc = thr & 15;
    int hgrp  = thr >> 4;
    int h0    = hgrp * 32 + i4 * 4;
    int bg    = btile * 16 + b_loc;

    float imin   = inp_min_p[0];
    float iscale = 1.0f / (inp_max_p[0] - imin);
    const float* xp = batch + ((size_t)bg * T_STEPS + tt) * 16;
    float xr[16];
#pragma unroll
    for (int k = 0; k < 16; ++k) xr[k] = (xp[k] - imin) * iscale;

    float out4[4];
#pragma unroll
    for (int e = 0; e < 4; ++e) {
        int h = h0 + e;
        float acc = b1[h];
        const float* wrow = W1 + h * 16;
#pragma unroll
        for (int k = 0; k < 16; ++k) acc = fmaf(xr[k], wrow[k], acc);
        out4[e] = acc / thr1[h];
    }
    size_t ob = (((size_t)tt * 8 + btile) * 256 + thr) * 32 + i4 * 4;
    f32x4 v = { out4[0], out4[1], out4[2], out4[3] };
    *(f32x4*)(cur1s + ob) = v;
}

// ---------------- kernel 0b: split W2 into bf16 hi + lo ----------------
__global__ __launch_bounds__(256) void k_split(const float* __restrict__ W2,
    unsigned short* __restrict__ W2hi, unsigned short* __restrict__ W2lo)
{
    int gid = blockIdx.x * 256 + threadIdx.x;       // 65536, 4 elems each
    f32x4 w = *(const f32x4*)(W2 + (size_t)gid * 4);
    unsigned short hi[4], lo[4];
#pragma unroll
    for (int e = 0; e < 4; ++e) {
        float wf = w[e];
        unsigned short h = f2bf(wf);
        float hf = __uint_as_float(((unsigned int)h) << 16);
        hi[e] = h;
        lo[e] = f2bf(wf - hf);
    }
    uint2 ph, pl;
    ph.x = (unsigned)hi[0] | ((unsigned)hi[1] << 16);
    ph.y = (unsigned)hi[2] | ((unsigned)hi[3] << 16);
    pl.x = (unsigned)lo[0] | ((unsigned)lo[1] << 16);
    pl.y = (unsigned)lo[2] | ((unsigned)lo[3] << 16);
    *(uint2*)(W2hi + (size_t)gid * 4) = ph;
    *(uint2*)(W2lo + (size_t)gid * 4) = pl;
}

// ---------------- main persistent kernel: LIF1 -> GEMM2(bf16 2-split MFMA) -> LIF2 -> spk2 bits ----
__global__ __launch_bounds__(256, 1) void k_main(
    const float* __restrict__ cur1s, const unsigned short* __restrict__ W2hi,
    const unsigned short* __restrict__ W2lo,
    const float* __restrict__ beta1, const float* __restrict__ b2,
    const float* __restrict__ beta2, const float* __restrict__ thr2,
    unsigned short* __restrict__ spkbits)
{
    __shared__ uint4 Abuf[2][1024];   // [kk 16][lane 64] 16B, double buffered (32 KB)
    __shared__ float Cbuf[1024];      // [ws 4][lane 64][reg 4] (4 KB)

    int tid   = threadIdx.x;
    int lane  = tid & 63;
    int w     = tid >> 6;             // wave id 0..3 = K-chunk
    int btile = blockIdx.x & 7;
    int slice = blockIdx.x >> 3;      // 0..31, 16 j's each

    // --- preload B fragments (W2 hi/lo) for this wave's K-chunk, once ---
    short8 bhi[4], blo[4];
    int n = slice * 16 + (lane & 15);
#pragma unroll
    for (int s = 0; s < 4; ++s) {
        int k0 = w * 128 + s * 32 + ((lane >> 4) & 3) * 8;
        bhi[s] = *(const short8*)(W2hi + (size_t)n * 512 + k0);
        blo[s] = *(const short8*)(W2lo + (size_t)n * 512 + k0);
    }

    // --- LIF2 params: this thread's item is (b=(lane>>4)*4+w, j=lane&15) ---
    int jg = slice * 16 + (lane & 15);
    float beta2r = fminf(fmaxf(beta2[jg], 0.0f), 1.0f);
    float thr2r  = thr2[jg];
    float nthr2  = -thr2r;
    float b2r    = b2[jg];
    float m2 = 0.0f, spk2f = 0.0f;

    // --- LIF1 params: thread owns (b_loc = tid&15, h = hgrp*32 + i) ---
    int b_loc = tid & 15;
    int hgrp  = tid >> 4;
    float beta1r[32];
#pragma unroll
    for (int i = 0; i < 32; ++i)
        beta1r[i] = fminf(fmaxf(beta1[hgrp * 32 + i], 0.0f), 1.0f);
    float m1[32], spk1f[32];
#pragma unroll
    for (int i = 0; i < 32; ++i) { m1[i] = 0.0f; spk1f[i] = 0.0f; }

    const float* curbase = cur1s + ((size_t)btile * 256 + tid) * 32;
    float curf[32], nxtf[32];
    {
        const f32x4* cp = (const f32x4*)curbase;
#pragma unroll
        for (int r = 0; r < 8; ++r) {
            f32x4 v = cp[r];
#pragma unroll
            for (int e = 0; e < 4; ++e) curf[r * 4 + e] = v[e];
        }
    }

#pragma unroll 1
    for (int ts = 0; ts < T_STEPS; ++ts) {
        int buf = ts & 1;
        // ---- LIF1 (scaled domain: thr == 1) + pack spikes as bf16 into A-layout LDS ----
        unsigned short u16v[32];
#pragma unroll
        for (int i = 0; i < 32; ++i) {
            float m = fmaf(beta1r[i], m1[i], curf[i]);
            m -= spk1f[i];                       // reset = previous spike
            bool sp = m > 1.0f;
            m1[i] = m;
            spk1f[i] = sp ? 1.0f : 0.0f;
            u16v[i] = sp ? (unsigned short)0x3F80 : (unsigned short)0;
        }
#pragma unroll
        for (int q = 0; q < 4; ++q) {
            uint4 pk;
            pk.x = (unsigned)u16v[q*8+0] | ((unsigned)u16v[q*8+1] << 16);
            pk.y = (unsigned)u16v[q*8+2] | ((unsigned)u16v[q*8+3] << 16);
            pk.z = (unsigned)u16v[q*8+4] | ((unsigned)u16v[q*8+5] << 16);
            pk.w = (unsigned)u16v[q*8+6] | ((unsigned)u16v[q*8+7] << 16);
            Abuf[buf][hgrp * 64 + (b_loc | (q << 4))] = pk;
        }
        // ---- prefetch next step's cur1 (completes during MFMA phase) ----
        {
            int tn = (ts + 1 < T_STEPS) ? ts + 1 : ts;
            const f32x4* cp = (const f32x4*)(curbase + (size_t)tn * 65536);
#pragma unroll
            for (int r = 0; r < 8; ++r) {
                f32x4 v = cp[r];
#pragma unroll
                for (int e = 0; e < 4; ++e) nxtf[r * 4 + e] = v[e];
            }
        }
        __syncthreads();

        // ---- layer2 GEMM: 16x16 tile, K-chunk of 128, hi+lo splits into one accumulator ----
        f32x4 C = { 0.f, 0.f, 0.f, 0.f };
#pragma unroll
        for (int s = 0; s < 4; ++s) {
            union { uint4 u; short8 s8; } cv;
            cv.u = Abuf[buf][(w * 4 + s) * 64 + lane];
            C = __builtin_amdgcn_mfma_f32_16x16x32_bf16(cv.s8, bhi[s], C, 0, 0, 0);
            C = __builtin_amdgcn_mfma_f32_16x16x32_bf16(cv.s8, blo[s], C, 0, 0, 0);
        }
        *(f32x4*)&Cbuf[(w * 64 + lane) * 4] = C;
        __syncthreads();

        // ---- K-reduce + LIF2 + spk2 bit emission ----
        float cur2 = b2r;
#pragma unroll
        for (int ws_ = 0; ws_ < 4; ++ws_) cur2 += Cbuf[ws_ * 256 + lane * 4 + w];
        m2 = fmaf(beta2r, m2, cur2);
        m2 = fmaf(spk2f, nthr2, m2);             // subtract reset (prev spike)
        bool sp2 = m2 > thr2r;
        spk2f = sp2 ? 1.0f : 0.0f;
        unsigned long long mask = __ballot(sp2);
        if (lane < 4) {
            unsigned short v = (unsigned short)(mask >> (lane * 16));
            spkbits[((size_t)ts * BATCH + btile * 16 + lane * 4 + w) * 32 + slice] = v;
        }
#pragma unroll
        for (int i = 0; i < 32; ++i) curf[i] = nxtf[i];
    }
}

// ---------------- kernel 3: action bit-GEMM + beta-weighted scan over t ----------------
__global__ __launch_bounds__(256) void k_act(
    const unsigned short* __restrict__ spkbits,
    const float* __restrict__ Wa, const float* __restrict__ ba,
    const float* __restrict__ beta_act_p, float* __restrict__ out)
{
    __shared__ f32x4 waT[512];
    __shared__ f32x4 sc[256];
    int tid = threadIdx.x;   // = timestep
    int b   = blockIdx.x;

    for (int j = tid; j < 512; j += 256) {
        f32x4 v = { Wa[j], Wa[512 + j], Wa[1024 + j], Wa[1536 + j] };
        waT[j] = v;
    }
    float bact = fminf(fmaxf(beta_act_p[0], 0.0f), 1.0f);
    f32x4 acc = { ba[0], ba[1], ba[2], ba[3] };
    __syncthreads();

    const unsigned short* sp = spkbits + ((size_t)tid * BATCH + b) * 32;
    unsigned int wbuf[16];
#pragma unroll
    for (int r = 0; r < 4; ++r) {
        uint4 v = *(const uint4*)(sp + r * 8);
        wbuf[r*4+0] = v.x; wbuf[r*4+1] = v.y; wbuf[r*4+2] = v.z; wbuf[r*4+3] = v.w;
    }
    for (int s = 0; s < 32; ++s) {
        unsigned int wd = (wbuf[s >> 1] >> ((s & 1) * 16)) & 0xFFFFu;
#pragma unroll
        for (int i = 0; i < 16; ++i) {
            float sel = ((wd >> i) & 1u) ? 1.0f : 0.0f;
            f32x4 wv = waT[s * 16 + i];
            acc[0] = fmaf(sel, wv[0], acc[0]);
            acc[1] = fmaf(sel, wv[1], acc[1]);
            acc[2] = fmaf(sel, wv[2], acc[2]);
            acc[3] = fmaf(sel, wv[3], acc[3]);
        }
    }
    sc[tid] = acc;
    __syncthreads();
    // Hillis-Steele weighted scan: x[t] += beta^d * x[t-d]
    float bd = bact;
    for (int d = 1; d < 256; d <<= 1) {
        f32x4 cv = sc[tid];
        f32x4 pv = { 0.f, 0.f, 0.f, 0.f };
        if (tid >= d) pv = sc[tid - d];
        __syncthreads();
        cv[0] = fmaf(bd, pv[0], cv[0]);
        cv[1] = fmaf(bd, pv[1], cv[1]);
        cv[2] = fmaf(bd, pv[2], cv[2]);
        cv[3] = fmaf(bd, pv[3], cv[3]);
        sc[tid] = cv;
        __syncthreads();
        bd *= bd;
    }
    f32x4 res = sc[tid];
    *(f32x4*)(out + (size_t)tid * 512 + b * 4) = res;
}

extern "C" void kernel_launch(void* const* d_in, const int* in_sizes, int n_in,
                              void* d_out, int out_size, void* d_ws, size_t ws_size,
                              hipStream_t stream)
{
    const float* batch    = (const float*)d_in[0];
    const float* W1       = (const float*)d_in[1];
    const float* b1       = (const float*)d_in[2];
    const float* beta1    = (const float*)d_in[3];
    const float* thr1     = (const float*)d_in[4];
    const float* W2       = (const float*)d_in[5];
    const float* b2       = (const float*)d_in[6];
    const float* beta2    = (const float*)d_in[7];
    const float* thr2     = (const float*)d_in[8];
    const float* Wa       = (const float*)d_in[9];
    const float* ba       = (const float*)d_in[10];
    const float* beta_act = (const float*)d_in[11];
    const float* inp_min  = (const float*)d_in[12];
    const float* inp_max  = (const float*)d_in[13];
    float* out            = (float*)d_out;

    char* ws = (char*)d_ws;
    float* cur1s            = (float*)ws;                                   // 64 MiB
    unsigned short* W2hi    = (unsigned short*)(ws + (64u << 20));          // 512 KiB
    unsigned short* W2lo    = (unsigned short*)(ws + (64u << 20) + (512u << 10));
    unsigned short* spkbits = (unsigned short*)(ws + (65u << 20));          // 2 MiB

    hipLaunchKernelGGL(k_cur1, dim3(16384), dim3(256), 0, stream,
                       batch, W1, b1, thr1, inp_min, inp_max, cur1s);
    hipLaunchKernelGGL(k_split, dim3(256), dim3(256), 0, stream, W2, W2hi, W2lo);
    hipLaunchKernelGGL(k_main, dim3(256), dim3(256), 0, stream,
                       cur1s, W2hi, W2lo, beta1, b2, beta2, thr2, spkbits);
    hipLaunchKernelGGL(k_act, dim3(128), dim3(256), 0, stream, spkbits, Wa, ba, beta_act, out);
}

// Round 3
// 445.847 us; speedup vs baseline: 1.3386x; 1.3386x over previous
//
#include <hip/hip_runtime.h>
#include <stdint.h>

typedef __attribute__((ext_vector_type(8))) short short8;
typedef __attribute__((ext_vector_type(4))) float f32x4;

#define T_STEPS 256
#define BATCH   128
#define HID     512

// LDS-visibility barrier that does NOT drain vmcnt: global prefetch stays in flight.
#define LDS_BARRIER() asm volatile("s_waitcnt lgkmcnt(0)\n\ts_barrier" ::: "memory")

static __device__ inline unsigned short f2bf(float f) {
    unsigned int u = __float_as_uint(f);
    unsigned int r = u + 0x7FFFu + ((u >> 16) & 1u);
    return (unsigned short)(r >> 16);
}

// ---- kernel 0: cur1s[t][btile][thr(512)][16] = (xn@W1^T + b1)/thr1, k_main thread order ----
__global__ __launch_bounds__(256) void k_cur1(const float* __restrict__ batch,
    const float* __restrict__ W1, const float* __restrict__ b1,
    const float* __restrict__ thr1, const float* __restrict__ inp_min_p,
    const float* __restrict__ inp_max_p, float* __restrict__ cur1s)
{
    int gid   = blockIdx.x * 256 + threadIdx.x;   // 4,194,304 total
    int j4    = gid & 3;
    int thr   = (gid >> 2) & 511;
    int btile = (gid >> 11) & 7;
    int tt    = gid >> 14;
    int b_loc = thr & 15;
    int hgrp  = thr >> 4;
    int h0    = hgrp * 16 + j4 * 4;
    int bg    = btile * 16 + b_loc;

    float imin   = inp_min_p[0];
    float iscale = 1.0f / (inp_max_p[0] - imin);
    const float* xp = batch + ((size_t)bg * T_STEPS + tt) * 16;
    float xr[16];
#pragma unroll
    for (int k = 0; k < 16; ++k) xr[k] = (xp[k] - imin) * iscale;

    float out4[4];
#pragma unroll
    for (int e = 0; e < 4; ++e) {
        int h = h0 + e;
        float acc = b1[h];
        const float* wrow = W1 + h * 16;
#pragma unroll
        for (int k = 0; k < 16; ++k) acc = fmaf(xr[k], wrow[k], acc);
        out4[e] = acc / thr1[h];
    }
    f32x4 v = { out4[0], out4[1], out4[2], out4[3] };
    *(f32x4*)(cur1s + (size_t)gid * 4) = v;
}

// ---- kernel 0b: split W2 into bf16 hi + lo ----
__global__ __launch_bounds__(256) void k_split(const float* __restrict__ W2,
    unsigned short* __restrict__ W2hi, unsigned short* __restrict__ W2lo)
{
    int gid = blockIdx.x * 256 + threadIdx.x;       // 65536, 4 elems each
    f32x4 w = *(const f32x4*)(W2 + (size_t)gid * 4);
    unsigned short hi[4], lo[4];
#pragma unroll
    for (int e = 0; e < 4; ++e) {
        float wf = w[e];
        unsigned short h = f2bf(wf);
        float hf = __uint_as_float(((unsigned int)h) << 16);
        hi[e] = h;
        lo[e] = f2bf(wf - hf);
    }
    uint2 ph, pl;
    ph.x = (unsigned)hi[0] | ((unsigned)hi[1] << 16);
    ph.y = (unsigned)hi[2] | ((unsigned)hi[3] << 16);
    pl.x = (unsigned)lo[0] | ((unsigned)lo[1] << 16);
    pl.y = (unsigned)lo[2] | ((unsigned)lo[3] << 16);
    *(uint2*)(W2hi + (size_t)gid * 4) = ph;
    *(uint2*)(W2lo + (size_t)gid * 4) = pl;
}

// ---- main persistent kernel: 512 threads (8 waves), K split 8 ways ----
__global__ __launch_bounds__(512, 2) void k_main(
    const float* __restrict__ cur1s, const unsigned short* __restrict__ W2hi,
    const unsigned short* __restrict__ W2lo,
    const float* __restrict__ beta1, const float* __restrict__ b2,
    const float* __restrict__ beta2, const float* __restrict__ thr2,
    unsigned short* __restrict__ spkbits)
{
    __shared__ uint4 Abuf[2][1024];   // [kk 16][frag-lane 64], double buffered (32 KB)
    __shared__ float Cbuf[2048];      // [r 4][w' 8][lane 64] (8 KB) — lane-stride-1 everywhere

    int tid   = threadIdx.x;
    int lane  = tid & 63;
    int w     = tid >> 6;             // wave id 0..7 = K-chunk of 64
    int btile = blockIdx.x & 7;
    int slice = blockIdx.x >> 3;      // 0..31, 16 j's each

    // LIF1 ownership: b_loc = tid&15, h = hgrp*16 + i (i<16)
    int b_loc = tid & 15;
    int hgrp  = tid >> 4;             // 0..31
    int kk    = hgrp >> 1;
    int qbase = (hgrp & 1) * 2;

    // issue t=0 cur1 loads ASAP
    const float* curbase = cur1s + ((size_t)btile * 512 + tid) * 16;
    f32x4 cA[4], cB[4];
    {
        const f32x4* cp = (const f32x4*)curbase;
#pragma unroll
        for (int r = 0; r < 4; ++r) cA[r] = cp[r];
    }

    // B fragments for this wave's K-chunk [w*64, w*64+64)
    short8 bhi[2], blo[2];
    int n = slice * 16 + (lane & 15);
#pragma unroll
    for (int s = 0; s < 2; ++s) {
        int k0 = w * 64 + s * 32 + ((lane >> 4) & 3) * 8;
        bhi[s] = *(const short8*)(W2hi + (size_t)n * 512 + k0);
        blo[s] = *(const short8*)(W2lo + (size_t)n * 512 + k0);
    }

    // LIF2 params (used by waves 0..3): item (b=(lane>>4)*4+w, j=lane&15)
    int jg = slice * 16 + (lane & 15);
    float beta2r = fminf(fmaxf(beta2[jg], 0.0f), 1.0f);
    float thr2r  = thr2[jg];
    float nthr2  = -thr2r;
    float b2r    = b2[jg];
    float m2 = 0.0f, spk2f = 0.0f;

    float beta1r[16], m1[16], spk1f[16];
#pragma unroll
    for (int i = 0; i < 16; ++i) {
        beta1r[i] = fminf(fmaxf(beta1[hgrp * 16 + i], 0.0f), 1.0f);
        m1[i] = 0.0f; spk1f[i] = 0.0f;
    }

    auto step = [&](int ts, f32x4* cur, f32x4* nxt) __attribute__((always_inline)) {
        int buf = ts & 1;
        // -- prefetch ts+1 (stays in flight across both barriers; consumed next step) --
        {
            int tn = (ts + 1 < T_STEPS) ? ts + 1 : ts;
            const f32x4* cp = (const f32x4*)(curbase + (size_t)tn * 65536);
#pragma unroll
            for (int r = 0; r < 4; ++r) nxt[r] = cp[r];
        }
        // -- LIF1 (scaled: thr==1) + pack spikes into A-frag LDS layout --
        unsigned short u16v[16];
#pragma unroll
        for (int i = 0; i < 16; ++i) {
            float m = fmaf(beta1r[i], m1[i], cur[i >> 2][i & 3]);
            m -= spk1f[i];
            bool sp = m > 1.0f;
            m1[i] = m;
            spk1f[i] = sp ? 1.0f : 0.0f;
            u16v[i] = sp ? (unsigned short)0x3F80 : (unsigned short)0;
        }
#pragma unroll
        for (int q = 0; q < 2; ++q) {
            uint4 pk;
            pk.x = (unsigned)u16v[q*8+0] | ((unsigned)u16v[q*8+1] << 16);
            pk.y = (unsigned)u16v[q*8+2] | ((unsigned)u16v[q*8+3] << 16);
            pk.z = (unsigned)u16v[q*8+4] | ((unsigned)u16v[q*8+5] << 16);
            pk.w = (unsigned)u16v[q*8+6] | ((unsigned)u16v[q*8+7] << 16);
            Abuf[buf][kk * 64 + (qbase + q) * 16 + b_loc] = pk;
        }
        LDS_BARRIER();

        // -- layer2 GEMM: this wave's K=64 chunk; hi/lo in separate accumulators --
        f32x4 Ch = { 0.f, 0.f, 0.f, 0.f };
        f32x4 Cl = { 0.f, 0.f, 0.f, 0.f };
#pragma unroll
        for (int s = 0; s < 2; ++s) {
            union { uint4 u; short8 s8; } cv;
            cv.u = Abuf[buf][(w * 2 + s) * 64 + lane];
            Ch = __builtin_amdgcn_mfma_f32_16x16x32_bf16(cv.s8, bhi[s], Ch, 0, 0, 0);
            Cl = __builtin_amdgcn_mfma_f32_16x16x32_bf16(cv.s8, blo[s], Cl, 0, 0, 0);
        }
#pragma unroll
        for (int r = 0; r < 4; ++r)
            Cbuf[r * 512 + w * 64 + lane] = Ch[r] + Cl[r];
        LDS_BARRIER();

        // -- K-reduce + LIF2 + spk2 bits (waves 0..3 only) --
        if (w < 4) {
            float cur2 = b2r;
#pragma unroll
            for (int wp = 0; wp < 8; ++wp) cur2 += Cbuf[w * 512 + wp * 64 + lane];
            m2 = fmaf(beta2r, m2, cur2);
            m2 = fmaf(spk2f, nthr2, m2);
            bool sp2 = m2 > thr2r;
            spk2f = sp2 ? 1.0f : 0.0f;
            unsigned long long mask = __ballot(sp2);
            if (lane < 4) {
                unsigned short v = (unsigned short)(mask >> (lane * 16));
                spkbits[((size_t)ts * BATCH + btile * 16 + lane * 4 + w) * 32 + slice] = v;
            }
        }
    };

#pragma unroll 1
    for (int ts = 0; ts < T_STEPS; ts += 2) {
        step(ts, cA, cB);
        step(ts + 1, cB, cA);
    }
}

// ---- kernel 3: action bit-GEMM + beta-weighted scan over t ----
__global__ __launch_bounds__(256) void k_act(
    const unsigned short* __restrict__ spkbits,
    const float* __restrict__ Wa, const float* __restrict__ ba,
    const float* __restrict__ beta_act_p, float* __restrict__ out)
{
    __shared__ f32x4 waT[512];
    __shared__ f32x4 sc[256];
    int tid = threadIdx.x;   // = timestep
    int b   = blockIdx.x;

    for (int j = tid; j < 512; j += 256) {
        f32x4 v = { Wa[j], Wa[512 + j], Wa[1024 + j], Wa[1536 + j] };
        waT[j] = v;
    }
    float bact = fminf(fmaxf(beta_act_p[0], 0.0f), 1.0f);
    f32x4 acc = { ba[0], ba[1], ba[2], ba[3] };
    __syncthreads();

    const unsigned short* sp = spkbits + ((size_t)tid * BATCH + b) * 32;
    unsigned int wbuf[16];
#pragma unroll
    for (int r = 0; r < 4; ++r) {
        uint4 v = *(const uint4*)(sp + r * 8);
        wbuf[r*4+0] = v.x; wbuf[r*4+1] = v.y; wbuf[r*4+2] = v.z; wbuf[r*4+3] = v.w;
    }
    for (int s = 0; s < 32; ++s) {
        unsigned int wd = (wbuf[s >> 1] >> ((s & 1) * 16)) & 0xFFFFu;
#pragma unroll
        for (int i = 0; i < 16; ++i) {
            float sel = ((wd >> i) & 1u) ? 1.0f : 0.0f;
            f32x4 wv = waT[s * 16 + i];
            acc[0] = fmaf(sel, wv[0], acc[0]);
            acc[1] = fmaf(sel, wv[1], acc[1]);
            acc[2] = fmaf(sel, wv[2], acc[2]);
            acc[3] = fmaf(sel, wv[3], acc[3]);
        }
    }
    sc[tid] = acc;
    __syncthreads();
    // Hillis-Steele weighted scan: x[t] += beta^d * x[t-d]
    float bd = bact;
    for (int d = 1; d < 256; d <<= 1) {
        f32x4 cv = sc[tid];
        f32x4 pv = { 0.f, 0.f, 0.f, 0.f };
        if (tid >= d) pv = sc[tid - d];
        __syncthreads();
        cv[0] = fmaf(bd, pv[0], cv[0]);
        cv[1] = fmaf(bd, pv[1], cv[1]);
        cv[2] = fmaf(bd, pv[2], cv[2]);
        cv[3] = fmaf(bd, pv[3], cv[3]);
        sc[tid] = cv;
        __syncthreads();
        bd *= bd;
    }
    f32x4 res = sc[tid];
    *(f32x4*)(out + (size_t)tid * 512 + b * 4) = res;
}

extern "C" void kernel_launch(void* const* d_in, const int* in_sizes, int n_in,
                              void* d_out, int out_size, void* d_ws, size_t ws_size,
                              hipStream_t stream)
{
    const float* batch    = (const float*)d_in[0];
    const float* W1       = (const float*)d_in[1];
    const float* b1       = (const float*)d_in[2];
    const float* beta1    = (const float*)d_in[3];
    const float* thr1     = (const float*)d_in[4];
    const float* W2       = (const float*)d_in[5];
    const float* b2       = (const float*)d_in[6];
    const float* beta2    = (const float*)d_in[7];
    const float* thr2     = (const float*)d_in[8];
    const float* Wa       = (const float*)d_in[9];
    const float* ba       = (const float*)d_in[10];
    const float* beta_act = (const float*)d_in[11];
    const float* inp_min  = (const float*)d_in[12];
    const float* inp_max  = (const float*)d_in[13];
    float* out            = (float*)d_out;

    char* ws = (char*)d_ws;
    float* cur1s            = (float*)ws;                                   // 64 MiB
    unsigned short* W2hi    = (unsigned short*)(ws + (64u << 20));          // 512 KiB
    unsigned short* W2lo    = (unsigned short*)(ws + (64u << 20) + (512u << 10));
    unsigned short* spkbits = (unsigned short*)(ws + (65u << 20));          // 2 MiB

    hipLaunchKernelGGL(k_cur1, dim3(16384), dim3(256), 0, stream,
                       batch, W1, b1, thr1, inp_min, inp_max, cur1s);
    hipLaunchKernelGGL(k_split, dim3(256), dim3(256), 0, stream, W2, W2hi, W2lo);
    hipLaunchKernelGGL(k_main, dim3(256), dim3(512), 0, stream,
                       cur1s, W2hi, W2lo, beta1, b2, beta2, thr2, spkbits);
    hipLaunchKernelGGL(k_act, dim3(128), dim3(256), 0, stream, spkbits, Wa, ba, beta_act, out);
}

// Round 4
// 358.542 us; speedup vs baseline: 1.6645x; 1.2435x over previous
//
#include <hip/hip_runtime.h>
#include <stdint.h>

typedef __attribute__((ext_vector_type(8))) short short8;
typedef __attribute__((ext_vector_type(4))) float f32x4;

#define T_STEPS 256
#define BATCH   128

// LDS-visibility barrier that does NOT drain vmcnt (global prefetch stays in flight)
#define LDS_BARRIER() asm volatile("s_waitcnt lgkmcnt(0)\n\ts_barrier" ::: "memory")

static __device__ inline unsigned short f2bf(float f) {   // RNE fp32->bf16 (W2 path, as R3)
    unsigned int u = __float_as_uint(f);
    unsigned int r = u + 0x7FFFu + ((u >> 16) & 1u);
    return (unsigned short)(r >> 16);
}
static __device__ inline unsigned pack_hi16(unsigned a, unsigned b) {
    // low ushort = a>>16, high ushort = b's high16
    return (a >> 16) | (b & 0xFFFF0000u);
}

// ---- prep: W2 -> bf16 hi/lo (blocks 0..255); W1 -> scaled 3-split rows + fused bias (blocks 256..257)
// W1rows[h][64]: [0..15]=Wh, [16..31]=Wm, [32..47]=Wl, [48..63]=0   (W'' = W1 * iscale / thr1[h])
// b1s[h] = (b1[h] - imin*iscale*rowsum(W1[h])) / thr1[h]
__global__ __launch_bounds__(256) void k_prep(
    const float* __restrict__ W2, const float* __restrict__ W1,
    const float* __restrict__ b1, const float* __restrict__ thr1,
    const float* __restrict__ imin_p, const float* __restrict__ imax_p,
    unsigned short* __restrict__ W2hi, unsigned short* __restrict__ W2lo,
    unsigned short* __restrict__ W1rows, float* __restrict__ b1s)
{
    int blk = blockIdx.x, tid = threadIdx.x;
    if (blk < 256) {
        int gid = blk * 256 + tid;          // 65536 threads, 4 elems each
        f32x4 wv = *(const f32x4*)(W2 + (size_t)gid * 4);
        unsigned short hi[4], lo[4];
#pragma unroll
        for (int e = 0; e < 4; ++e) {
            float wf = wv[e];
            unsigned short h = f2bf(wf);
            float hf = __uint_as_float(((unsigned int)h) << 16);
            hi[e] = h;
            lo[e] = f2bf(wf - hf);
        }
        uint2 ph, pl;
        ph.x = (unsigned)hi[0] | ((unsigned)hi[1] << 16);
        ph.y = (unsigned)hi[2] | ((unsigned)hi[3] << 16);
        pl.x = (unsigned)lo[0] | ((unsigned)lo[1] << 16);
        pl.y = (unsigned)lo[2] | ((unsigned)lo[3] << 16);
        *(uint2*)(W2hi + (size_t)gid * 4) = ph;
        *(uint2*)(W2lo + (size_t)gid * 4) = pl;
    } else {
        int h = (blk - 256) * 256 + tid;    // 512 rows
        float imin = imin_p[0];
        float s = 1.0f / (imax_p[0] - imin);
        float th = thr1[h];
        float wsc = s / th;
        float rs = 0.0f;
        unsigned short row[64];
#pragma unroll
        for (int k = 0; k < 16; ++k) {
            float wraw = W1[h * 16 + k];
            rs += wraw;
            float wv = wraw * wsc;
            unsigned a = __float_as_uint(wv) & 0xFFFF0000u;
            float r1 = wv - __uint_as_float(a);
            unsigned m = __float_as_uint(r1) & 0xFFFF0000u;
            float r2 = r1 - __uint_as_float(m);
            unsigned l = __float_as_uint(r2) & 0xFFFF0000u;
            row[k]      = (unsigned short)(a >> 16);
            row[16 + k] = (unsigned short)(m >> 16);
            row[32 + k] = (unsigned short)(l >> 16);
            row[48 + k] = 0;
        }
        b1s[h] = (b1[h] - imin * s * rs) / th;
        uint4* dst = (uint4*)(W1rows + (size_t)h * 64);
#pragma unroll
        for (int i = 0; i < 8; ++i) dst[i] = ((uint4*)row)[i];
    }
}

// ---- fused main kernel: GEMM1(MFMA) -> LIF1 -> intra-wave shuffle -> GEMM2 -> [1 barrier] -> LIF2
__global__ __launch_bounds__(512, 2) void k_main(
    const float* __restrict__ batch,
    const unsigned short* __restrict__ W2hi, const unsigned short* __restrict__ W2lo,
    const unsigned short* __restrict__ W1rows, const float* __restrict__ b1s,
    const float* __restrict__ beta1, const float* __restrict__ b2,
    const float* __restrict__ beta2, const float* __restrict__ thr2,
    unsigned short* __restrict__ spkbits)
{
    __shared__ unsigned char Awm[8][2048];  // per-wave spike staging (wave-private, no barrier)
    __shared__ float Cbuf[2][2048];         // [buf][r 4][w 8][lane 64], step-parity double buffer

    int tid  = threadIdx.x;
    int lane = tid & 63;
    int w    = tid >> 6;                    // wave id 0..7 = K-chunk of 64 (and GEMM1 h-chunk)
    int q    = lane >> 4;
    int m15  = lane & 15;
    int btile = blockIdx.x & 7;
    int slice = blockIdx.x >> 3;            // 0..31

    // x loads: B-frag lane (n=b=m15, k=q*8+j); [xh|xh] duplication => address uses q&1
    const float* xbase = batch + ((size_t)(btile * 16 + m15) * T_STEPS) * 16 + (q & 1) * 8;
    f32x4 xc[2], xn[2];
    xc[0] = *(const f32x4*)(xbase + 0);
    xc[1] = *(const f32x4*)(xbase + 4);

    // W2 B-frags for this wave's K-chunk (R3-proven layout)
    short8 bhi[2], blo[2];
    {
        int n = slice * 16 + m15;
#pragma unroll
        for (int s = 0; s < 2; ++s) {
            int k0 = w * 64 + s * 32 + q * 8;
            bhi[s] = *(const short8*)(W2hi + (size_t)n * 512 + k0);
            blo[s] = *(const short8*)(W2lo + (size_t)n * 512 + k0);
        }
    }
    // W1 A-frags: A1 = [Wh|Wm] along K, A2 = [Wl|0] (pad row makes q>=2 load zeros)
    short8 A1[4], A2[4];
#pragma unroll
    for (int c = 0; c < 4; ++c) {
        int h = w * 64 + c * 16 + m15;
        A1[c] = *(const short8*)(W1rows + (size_t)h * 64 + q * 8);
        A2[c] = *(const short8*)(W1rows + (size_t)h * 64 + 32 + q * 8);
    }
    // LIF1 per-lane params: state (b=m15, h = w*64 + c*16 + q*4 + r)
    f32x4 b14[4], bet1[4];
#pragma unroll
    for (int c = 0; c < 4; ++c) {
        int h = w * 64 + c * 16 + q * 4;
        b14[c] = *(const f32x4*)(b1s + h);
        f32x4 bb = *(const f32x4*)(beta1 + h);
#pragma unroll
        for (int r = 0; r < 4; ++r) bet1[c][r] = fminf(fmaxf(bb[r], 0.0f), 1.0f);
    }
    float m1[16], spk1f[16];
#pragma unroll
    for (int i = 0; i < 16; ++i) { m1[i] = 0.0f; spk1f[i] = 0.0f; }

    // LIF2 params (waves 0..3): item (b = (lane>>4)*4 + w, j = m15)
    int jg = slice * 16 + m15;
    float beta2r = fminf(fmaxf(beta2[jg], 0.0f), 1.0f);
    float thr2r  = thr2[jg];
    float nthr2  = -thr2r;
    float b2r    = b2[jg];
    float m2 = 0.0f, spk2f = 0.0f;

    unsigned char* myAw = Awm[w];
    int q2 = q >> 1, qo = (q & 1) * 8;

    auto body = [&](int ts, f32x4* xcur, f32x4* xnx) __attribute__((always_inline)) {
        int buf = ts & 1;
        // prefetch next step's x (stays in flight across the barrier)
        int tn = (ts + 1 < T_STEPS) ? ts + 1 : T_STEPS - 1;
        xnx[0] = *(const f32x4*)(xbase + (size_t)tn * 16);
        xnx[1] = *(const f32x4*)(xbase + (size_t)tn * 16 + 4);

        // exact 3-way bf16 split of x (trunc split: xh+xm+xl == x to ~2^-26)
        unsigned uh[8], um[8], ul[8];
#pragma unroll
        for (int e = 0; e < 8; ++e) {
            float xv = xcur[e >> 2][e & 3];
            unsigned a = __float_as_uint(xv) & 0xFFFF0000u;
            float r1 = xv - __uint_as_float(a);
            unsigned m = __float_as_uint(r1) & 0xFFFF0000u;
            float r2 = r1 - __uint_as_float(m);
            unsigned l = __float_as_uint(r2) & 0xFFFF0000u;
            uh[e] = a; um[e] = m; ul[e] = l;
        }
        union { unsigned u[4]; short8 s; } Xh, Xm, Xl;
#pragma unroll
        for (int p = 0; p < 4; ++p) {
            Xh.u[p] = pack_hi16(uh[2 * p], uh[2 * p + 1]);
            Xm.u[p] = pack_hi16(um[2 * p], um[2 * p + 1]);
            Xl.u[p] = pack_hi16(ul[2 * p], ul[2 * p + 1]);
        }
        // GEMM1: cur1 = x @ W1''^T + b1s  (4 chunks of 16 h; 4 MFMA each)
        f32x4 D[4];
#pragma unroll
        for (int c = 0; c < 4; ++c) D[c] = b14[c];
#pragma unroll
        for (int c = 0; c < 4; ++c) D[c] = __builtin_amdgcn_mfma_f32_16x16x32_bf16(A1[c], Xh.s, D[c], 0, 0, 0);
#pragma unroll
        for (int c = 0; c < 4; ++c) D[c] = __builtin_amdgcn_mfma_f32_16x16x32_bf16(A1[c], Xm.s, D[c], 0, 0, 0);
#pragma unroll
        for (int c = 0; c < 4; ++c) D[c] = __builtin_amdgcn_mfma_f32_16x16x32_bf16(A1[c], Xl.s, D[c], 0, 0, 0);
#pragma unroll
        for (int c = 0; c < 4; ++c) D[c] = __builtin_amdgcn_mfma_f32_16x16x32_bf16(A2[c], Xh.s, D[c], 0, 0, 0);
        // LIF1 (scaled: thr == 1), spike float doubles as bf16 source (1.0f>>16 == 0x3F80)
#pragma unroll
        for (int i = 0; i < 16; ++i) {
            int c = i >> 2, r = i & 3;
            float mv = fmaf(bet1[c][r], m1[i], D[c][r]);
            mv -= spk1f[i];
            bool sp = mv > 1.0f;
            m1[i] = mv;
            spk1f[i] = sp ? 1.0f : 0.0f;
        }
        // intra-wave shuffle: write spikes (b=m15, h-local=c*16+q*4+r) into consumer A-frag order
#pragma unroll
        for (int c = 0; c < 4; ++c) {
            uint2 pk;
            pk.x = pack_hi16(__float_as_uint(spk1f[c * 4 + 0]), __float_as_uint(spk1f[c * 4 + 1]));
            pk.y = pack_hi16(__float_as_uint(spk1f[c * 4 + 2]), __float_as_uint(spk1f[c * 4 + 3]));
            int lc = m15 + ((c & 1) * 2 + q2) * 16;
            *(uint2*)(myAw + (c >> 1) * 1024 + lc * 16 + qo) = pk;
        }
        // read own A2 frags (wave-private LDS; in-order per-wave DS pipe, no barrier)
        union { uint4 u; short8 s; } a2f0, a2f1;
        a2f0.u = *(uint4*)(myAw + lane * 16);
        a2f1.u = *(uint4*)(myAw + 1024 + lane * 16);
        // GEMM2 partial: this wave's K=64 chunk
        f32x4 Ch = { 0.f, 0.f, 0.f, 0.f }, Cl = { 0.f, 0.f, 0.f, 0.f };
        Ch = __builtin_amdgcn_mfma_f32_16x16x32_bf16(a2f0.s, bhi[0], Ch, 0, 0, 0);
        Cl = __builtin_amdgcn_mfma_f32_16x16x32_bf16(a2f0.s, blo[0], Cl, 0, 0, 0);
        Ch = __builtin_amdgcn_mfma_f32_16x16x32_bf16(a2f1.s, bhi[1], Ch, 0, 0, 0);
        Cl = __builtin_amdgcn_mfma_f32_16x16x32_bf16(a2f1.s, blo[1], Cl, 0, 0, 0);
#pragma unroll
        for (int r = 0; r < 4; ++r)
            Cbuf[buf][r * 512 + w * 64 + lane] = Ch[r] + Cl[r];
        LDS_BARRIER();
        // K-reduce + LIF2 + spike-bit emission (waves 0..3)
        if (w < 4) {
            float cur2 = b2r;
#pragma unroll
            for (int wp = 0; wp < 8; ++wp) cur2 += Cbuf[buf][w * 512 + wp * 64 + lane];
            m2 = fmaf(beta2r, m2, cur2);
            m2 = fmaf(spk2f, nthr2, m2);
            bool sp2 = m2 > thr2r;
            spk2f = sp2 ? 1.0f : 0.0f;
            unsigned long long mask = __ballot(sp2);
            if (lane < 4) {
                unsigned short v = (unsigned short)(mask >> (lane * 16));
                spkbits[((size_t)ts * BATCH + btile * 16 + lane * 4 + w) * 32 + slice] = v;
            }
        }
    };

#pragma unroll 1
    for (int ts = 0; ts < T_STEPS; ts += 2) {
        body(ts, xc, xn);
        body(ts + 1, xn, xc);
    }
}

// ---- action bit-GEMM + beta-weighted scan over t (unchanged, R3-proven) ----
__global__ __launch_bounds__(256) void k_act(
    const unsigned short* __restrict__ spkbits,
    const float* __restrict__ Wa, const float* __restrict__ ba,
    const float* __restrict__ beta_act_p, float* __restrict__ out)
{
    __shared__ f32x4 waT[512];
    __shared__ f32x4 sc[256];
    int tid = threadIdx.x;   // = timestep
    int b   = blockIdx.x;

    for (int j = tid; j < 512; j += 256) {
        f32x4 v = { Wa[j], Wa[512 + j], Wa[1024 + j], Wa[1536 + j] };
        waT[j] = v;
    }
    float bact = fminf(fmaxf(beta_act_p[0], 0.0f), 1.0f);
    f32x4 acc = { ba[0], ba[1], ba[2], ba[3] };
    __syncthreads();

    const unsigned short* sp = spkbits + ((size_t)tid * BATCH + b) * 32;
    unsigned int wbuf[16];
#pragma unroll
    for (int r = 0; r < 4; ++r) {
        uint4 v = *(const uint4*)(sp + r * 8);
        wbuf[r*4+0] = v.x; wbuf[r*4+1] = v.y; wbuf[r*4+2] = v.z; wbuf[r*4+3] = v.w;
    }
    for (int s = 0; s < 32; ++s) {
        unsigned int wd = (wbuf[s >> 1] >> ((s & 1) * 16)) & 0xFFFFu;
#pragma unroll
        for (int i = 0; i < 16; ++i) {
            float sel = ((wd >> i) & 1u) ? 1.0f : 0.0f;
            f32x4 wv = waT[s * 16 + i];
            acc[0] = fmaf(sel, wv[0], acc[0]);
            acc[1] = fmaf(sel, wv[1], acc[1]);
            acc[2] = fmaf(sel, wv[2], acc[2]);
            acc[3] = fmaf(sel, wv[3], acc[3]);
        }
    }
    sc[tid] = acc;
    __syncthreads();
    float bd = bact;
    for (int d = 1; d < 256; d <<= 1) {
        f32x4 cv = sc[tid];
        f32x4 pv = { 0.f, 0.f, 0.f, 0.f };
        if (tid >= d) pv = sc[tid - d];
        __syncthreads();
        cv[0] = fmaf(bd, pv[0], cv[0]);
        cv[1] = fmaf(bd, pv[1], cv[1]);
        cv[2] = fmaf(bd, pv[2], cv[2]);
        cv[3] = fmaf(bd, pv[3], cv[3]);
        sc[tid] = cv;
        __syncthreads();
        bd *= bd;
    }
    f32x4 res = sc[tid];
    *(f32x4*)(out + (size_t)tid * 512 + b * 4) = res;
}

extern "C" void kernel_launch(void* const* d_in, const int* in_sizes, int n_in,
                              void* d_out, int out_size, void* d_ws, size_t ws_size,
                              hipStream_t stream)
{
    const float* batch    = (const float*)d_in[0];
    const float* W1       = (const float*)d_in[1];
    const float* b1       = (const float*)d_in[2];
    const float* beta1    = (const float*)d_in[3];
    const float* thr1     = (const float*)d_in[4];
    const float* W2       = (const float*)d_in[5];
    const float* b2       = (const float*)d_in[6];
    const float* beta2    = (const float*)d_in[7];
    const float* thr2     = (const float*)d_in[8];
    const float* Wa       = (const float*)d_in[9];
    const float* ba       = (const float*)d_in[10];
    const float* beta_act = (const float*)d_in[11];
    const float* inp_min  = (const float*)d_in[12];
    const float* inp_max  = (const float*)d_in[13];
    float* out            = (float*)d_out;

    char* ws = (char*)d_ws;
    unsigned short* W2hi    = (unsigned short*)ws;                          // 512 KiB
    unsigned short* W2lo    = (unsigned short*)(ws + (512u << 10));         // 512 KiB
    unsigned short* W1rows  = (unsigned short*)(ws + (1u << 20));           // 64 KiB
    float*          b1s     = (float*)(ws + (1u << 20) + (64u << 10));      // 2 KiB
    unsigned short* spkbits = (unsigned short*)(ws + (2u << 20));           // 2 MiB

    hipLaunchKernelGGL(k_prep, dim3(258), dim3(256), 0, stream,
                       W2, W1, b1, thr1, inp_min, inp_max, W2hi, W2lo, W1rows, b1s);
    hipLaunchKernelGGL(k_main, dim3(256), dim3(512), 0, stream,
                       batch, W2hi, W2lo, W1rows, b1s, beta1, b2, beta2, thr2, spkbits);
    hipLaunchKernelGGL(k_act, dim3(128), dim3(256), 0, stream, spkbits, Wa, ba, beta_act, out);
}

// Round 5
// 308.684 us; speedup vs baseline: 1.9334x; 1.1615x over previous
//
#include <hip/hip_runtime.h>
#include <stdint.h>

typedef __attribute__((ext_vector_type(8))) short short8;
typedef __attribute__((ext_vector_type(4))) float f32x4;

#define T_STEPS 256
#define BATCH   128

// LDS-visibility barrier that does NOT drain vmcnt (global prefetch stays in flight)
#define LDS_BARRIER() asm volatile("s_waitcnt lgkmcnt(0)\n\ts_barrier" ::: "memory")

static __device__ inline unsigned short f2bf(float f) {   // RNE fp32->bf16 (W2 hi/lo path)
    unsigned int u = __float_as_uint(f);
    unsigned int r = u + 0x7FFFu + ((u >> 16) & 1u);
    return (unsigned short)(r >> 16);
}
static __device__ inline unsigned pack_hi16(unsigned a, unsigned b) {
    return (a >> 16) | (b & 0xFFFF0000u);
}

// ---- k_prep: blocks 0..255 -> W2 hi/lo split; 256..257 -> W1 3-split rows (scaled 1/thr1);
//      blocks 258..769 -> X B-fragments (normalized, exact 3-way bf16 trunc split)
// W1rows[h][64]: [0..15]=Wh, [16..31]=Wm, [32..47]=Wl, [48..63]=0  (W' = W1 / thr1[h])
// Xf[t][btile][frag4][lane64] 16B: B1=[xh|xh], B2=[xm|xm], B3=[xl|xh], B4=[xl|xm]
__global__ __launch_bounds__(256) void k_prep(
    const float* __restrict__ W2, const float* __restrict__ W1,
    const float* __restrict__ b1, const float* __restrict__ thr1,
    const float* __restrict__ imin_p, const float* __restrict__ imax_p,
    const float* __restrict__ batch,
    unsigned short* __restrict__ W2hi, unsigned short* __restrict__ W2lo,
    unsigned short* __restrict__ W1rows, float* __restrict__ b1s,
    unsigned short* __restrict__ Xf)
{
    int blk = blockIdx.x, tid = threadIdx.x;
    if (blk < 256) {
        int gid = blk * 256 + tid;          // 65536 threads, 4 elems each
        f32x4 wv = *(const f32x4*)(W2 + (size_t)gid * 4);
        unsigned short hi[4], lo[4];
#pragma unroll
        for (int e = 0; e < 4; ++e) {
            float wf = wv[e];
            unsigned short h = f2bf(wf);
            float hf = __uint_as_float(((unsigned int)h) << 16);
            hi[e] = h;
            lo[e] = f2bf(wf - hf);
        }
        uint2 ph, pl;
        ph.x = (unsigned)hi[0] | ((unsigned)hi[1] << 16);
        ph.y = (unsigned)hi[2] | ((unsigned)hi[3] << 16);
        pl.x = (unsigned)lo[0] | ((unsigned)lo[1] << 16);
        pl.y = (unsigned)lo[2] | ((unsigned)lo[3] << 16);
        *(uint2*)(W2hi + (size_t)gid * 4) = ph;
        *(uint2*)(W2lo + (size_t)gid * 4) = pl;
    } else if (blk < 258) {
        int h = (blk - 256) * 256 + tid;    // 512 rows
        float wsc = 1.0f / thr1[h];
        unsigned short row[64];
#pragma unroll
        for (int k = 0; k < 16; ++k) {
            float wv = W1[h * 16 + k] * wsc;
            unsigned a = __float_as_uint(wv) & 0xFFFF0000u;
            float r1 = wv - __uint_as_float(a);
            unsigned m = __float_as_uint(r1) & 0xFFFF0000u;
            float r2 = r1 - __uint_as_float(m);
            unsigned l = __float_as_uint(r2) & 0xFFFF0000u;
            row[k]      = (unsigned short)(a >> 16);
            row[16 + k] = (unsigned short)(m >> 16);
            row[32 + k] = (unsigned short)(l >> 16);
            row[48 + k] = 0;
        }
        b1s[h] = b1[h] * wsc;
        uint4* dst = (uint4*)(W1rows + (size_t)h * 64);
#pragma unroll
        for (int i = 0; i < 8; ++i) dst[i] = ((uint4*)row)[i];
    } else {
        int gid   = (blk - 258) * 256 + tid;   // 131072 = 256t * 8btile * 64lane
        int lane  = gid & 63;
        int btile = (gid >> 6) & 7;
        int t     = gid >> 9;
        int q     = lane >> 4, m15 = lane & 15;
        int b     = btile * 16 + m15;
        float imin = imin_p[0];
        float isc  = 1.0f / (imax_p[0] - imin);
        const float* xp = batch + ((size_t)b * T_STEPS + t) * 16 + (q & 1) * 8;
        unsigned uh[8], um[8], ul[8];
#pragma unroll
        for (int j = 0; j < 8; ++j) {
            float xv = (xp[j] - imin) * isc;
            unsigned a = __float_as_uint(xv) & 0xFFFF0000u;
            float r1 = xv - __uint_as_float(a);
            unsigned m = __float_as_uint(r1) & 0xFFFF0000u;
            float r2 = r1 - __uint_as_float(m);
            unsigned l = __float_as_uint(r2) & 0xFFFF0000u;
            uh[j] = a; um[j] = m; ul[j] = l;
        }
        uint4 B1, B2, XL;
        B1.x = pack_hi16(uh[0], uh[1]); B1.y = pack_hi16(uh[2], uh[3]);
        B1.z = pack_hi16(uh[4], uh[5]); B1.w = pack_hi16(uh[6], uh[7]);
        B2.x = pack_hi16(um[0], um[1]); B2.y = pack_hi16(um[2], um[3]);
        B2.z = pack_hi16(um[4], um[5]); B2.w = pack_hi16(um[6], um[7]);
        XL.x = pack_hi16(ul[0], ul[1]); XL.y = pack_hi16(ul[2], ul[3]);
        XL.z = pack_hi16(ul[4], ul[5]); XL.w = pack_hi16(ul[6], ul[7]);
        uint4 B3 = (q < 2) ? XL : B1;   // [xl|xh]
        uint4 B4 = (q < 2) ? XL : B2;   // [xl|xm]
        unsigned short* dst = Xf + (((size_t)t * 8 + btile) * 4) * 512 + lane * 8;
        *(uint4*)(dst +    0) = B1;
        *(uint4*)(dst +  512) = B2;
        *(uint4*)(dst + 1024) = B3;
        *(uint4*)(dst + 1536) = B4;
    }
}

// ---- main: 1024 threads (16 waves, 4/SIMD), K split 16 ways; 1 barrier/step
__global__ __launch_bounds__(1024, 4) void k_main(
    const unsigned short* __restrict__ Xf,
    const unsigned short* __restrict__ W2hi, const unsigned short* __restrict__ W2lo,
    const unsigned short* __restrict__ W1rows, const float* __restrict__ b1s,
    const float* __restrict__ beta1, const float* __restrict__ b2,
    const float* __restrict__ beta2, const float* __restrict__ thr2,
    unsigned short* __restrict__ spkbits)
{
    __shared__ unsigned short Aw[8192];   // 16 waves x 1KB wave-private spike staging
    __shared__ float Cbuf[2][4096];       // [buf][r 4][wp 16][lane 64]

    int tid  = threadIdx.x;
    int lane = tid & 63;
    int w    = tid >> 6;                  // 0..15: K-chunk of 32 (and GEMM1 h-chunk of 32)
    int q    = lane >> 4, m15 = lane & 15;
    int btile = blockIdx.x & 7;
    int slice = blockIdx.x >> 3;

    // W1 A-frags: A1=[Wh|Wm], A2=[Wh|Wl], A3=[Wm|Wl]
    short8 A1[2], A2[2], A3[2];
#pragma unroll
    for (int c = 0; c < 2; ++c) {
        const unsigned short* rp = W1rows + (size_t)(w * 32 + c * 16 + m15) * 64;
        A1[c] = *(const short8*)(rp + q * 8);
        A2[c] = *(const short8*)(rp + q * 8 + (q >> 1) * 16);
        A3[c] = *(const short8*)(rp + 16 + q * 8);
    }
    // W2 B-frags for K-window [w*32, w*32+32)
    int jg = slice * 16 + m15;
    short8 bhi = *(const short8*)(W2hi + (size_t)jg * 512 + w * 32 + q * 8);
    short8 blo = *(const short8*)(W2lo + (size_t)jg * 512 + w * 32 + q * 8);

    // LIF1 params: states (b=m15, h = w*32 + c*16 + q*4 + r)
    f32x4 b14[2], bet1[2];
#pragma unroll
    for (int c = 0; c < 2; ++c) {
        int h0 = w * 32 + c * 16 + q * 4;
        b14[c] = *(const f32x4*)(b1s + h0);
        f32x4 bb = *(const f32x4*)(beta1 + h0);
#pragma unroll
        for (int r = 0; r < 4; ++r) bet1[c][r] = fminf(fmaxf(bb[r], 0.0f), 1.0f);
    }
    float m1[8], spk1f[8];
#pragma unroll
    for (int i = 0; i < 8; ++i) { m1[i] = 0.0f; spk1f[i] = 0.0f; }

    // LIF2 (waves 0..3): item (b = q*4 + w, j = jg)
    float beta2r = fminf(fmaxf(beta2[jg], 0.0f), 1.0f);
    float thr2r  = thr2[jg];
    float nthr2  = -thr2r;
    float b2r    = b2[jg];
    float m2 = 0.0f, spk2f = 0.0f;

    // X frags
    const unsigned short* xbase = Xf + ((size_t)btile * 4) * 512 + lane * 8;
    uint4 xc[4], xn[4];
#pragma unroll
    for (int f = 0; f < 4; ++f) xc[f] = *(const uint4*)(xbase + f * 512);

    unsigned short* myAw = Aw + w * 512;
    int wr0 = (0 * 2 + (q >> 1)) * 128 + (m15 ^ (q >> 1)) * 8 + (q & 1) * 4;
    int wr1 = (1 * 2 + (q >> 1)) * 128 + (m15 ^ (q >> 1)) * 8 + (q & 1) * 4;
    int rdo = (q * 16 + (m15 ^ (q & 1))) * 8;

    auto body = [&](int ts, uint4* xcur, uint4* xnx) __attribute__((always_inline)) {
        int buf = ts & 1;
        // prefetch t+1 X frags (in flight across the barrier)
        int tn = (ts + 1 < T_STEPS) ? ts + 1 : ts;
        const unsigned short* xp = xbase + (size_t)tn * 16384;
#pragma unroll
        for (int f = 0; f < 4; ++f) xnx[f] = *(const uint4*)(xp + f * 512);

        // GEMM1: 4-term split, 8 MFMA
        union { uint4 u; short8 s; } Bf[4];
#pragma unroll
        for (int f = 0; f < 4; ++f) Bf[f].u = xcur[f];
        f32x4 D[2];
#pragma unroll
        for (int c = 0; c < 2; ++c) {
            D[c] = b14[c];
            D[c] = __builtin_amdgcn_mfma_f32_16x16x32_bf16(A1[c], Bf[0].s, D[c], 0, 0, 0);
            D[c] = __builtin_amdgcn_mfma_f32_16x16x32_bf16(A1[c], Bf[1].s, D[c], 0, 0, 0);
            D[c] = __builtin_amdgcn_mfma_f32_16x16x32_bf16(A2[c], Bf[2].s, D[c], 0, 0, 0);
            D[c] = __builtin_amdgcn_mfma_f32_16x16x32_bf16(A3[c], Bf[3].s, D[c], 0, 0, 0);
        }
        // LIF1 (scaled: thr == 1)
#pragma unroll
        for (int i = 0; i < 8; ++i) {
            int c = i >> 2, r = i & 3;
            float mv = fmaf(bet1[c][r], m1[i], D[c][r]);
            mv -= spk1f[i];
            bool sp = mv > 1.0f;
            m1[i] = mv;
            spk1f[i] = sp ? 1.0f : 0.0f;
        }
        // spikes -> wave-private LDS in consumer A-frag order (XOR-swizzled)
        {
            uint2 pk0, pk1;
            pk0.x = pack_hi16(__float_as_uint(spk1f[0]), __float_as_uint(spk1f[1]));
            pk0.y = pack_hi16(__float_as_uint(spk1f[2]), __float_as_uint(spk1f[3]));
            pk1.x = pack_hi16(__float_as_uint(spk1f[4]), __float_as_uint(spk1f[5]));
            pk1.y = pack_hi16(__float_as_uint(spk1f[6]), __float_as_uint(spk1f[7]));
            *(uint2*)(myAw + wr0) = pk0;
            *(uint2*)(myAw + wr1) = pk1;
        }
        union { uint4 u; short8 s; } af;
        af.u = *(uint4*)(myAw + rdo);
        // GEMM2: K=32 chunk, hi then lo chained
        f32x4 C2 = { 0.f, 0.f, 0.f, 0.f };
        C2 = __builtin_amdgcn_mfma_f32_16x16x32_bf16(af.s, bhi, C2, 0, 0, 0);
        C2 = __builtin_amdgcn_mfma_f32_16x16x32_bf16(af.s, blo, C2, 0, 0, 0);
#pragma unroll
        for (int r = 0; r < 4; ++r)
            Cbuf[buf][r * 1024 + w * 64 + lane] = C2[r];
        LDS_BARRIER();
        // K-reduce (16 partials) + LIF2 + spike bits (waves 0..3; others run ahead)
        if (w < 4) {
            float cur2 = b2r;
#pragma unroll
            for (int wp = 0; wp < 16; ++wp) cur2 += Cbuf[buf][w * 1024 + wp * 64 + lane];
            m2 = fmaf(beta2r, m2, cur2);
            m2 = fmaf(spk2f, nthr2, m2);
            bool sp2 = m2 > thr2r;
            spk2f = sp2 ? 1.0f : 0.0f;
            unsigned long long mask = __ballot(sp2);
            if (lane < 4) {
                unsigned short v = (unsigned short)(mask >> (lane * 16));
                spkbits[((size_t)ts * BATCH + btile * 16 + lane * 4 + w) * 32 + slice] = v;
            }
        }
    };

#pragma unroll 1
    for (int ts = 0; ts < T_STEPS; ts += 2) {
        body(ts, xc, xn);
        body(ts + 1, xn, xc);
    }
}

// ---- action bit-GEMM + beta-weighted scan over t (R3/R4-proven) ----
__global__ __launch_bounds__(256) void k_act(
    const unsigned short* __restrict__ spkbits,
    const float* __restrict__ Wa, const float* __restrict__ ba,
    const float* __restrict__ beta_act_p, float* __restrict__ out)
{
    __shared__ f32x4 waT[512];
    __shared__ f32x4 sc[256];
    int tid = threadIdx.x;   // = timestep
    int b   = blockIdx.x;

    for (int j = tid; j < 512; j += 256) {
        f32x4 v = { Wa[j], Wa[512 + j], Wa[1024 + j], Wa[1536 + j] };
        waT[j] = v;
    }
    float bact = fminf(fmaxf(beta_act_p[0], 0.0f), 1.0f);
    f32x4 acc = { ba[0], ba[1], ba[2], ba[3] };
    __syncthreads();

    const unsigned short* sp = spkbits + ((size_t)tid * BATCH + b) * 32;
    unsigned int wbuf[16];
#pragma unroll
    for (int r = 0; r < 4; ++r) {
        uint4 v = *(const uint4*)(sp + r * 8);
        wbuf[r*4+0] = v.x; wbuf[r*4+1] = v.y; wbuf[r*4+2] = v.z; wbuf[r*4+3] = v.w;
    }
    for (int s = 0; s < 32; ++s) {
        unsigned int wd = (wbuf[s >> 1] >> ((s & 1) * 16)) & 0xFFFFu;
#pragma unroll
        for (int i = 0; i < 16; ++i) {
            float sel = ((wd >> i) & 1u) ? 1.0f : 0.0f;
            f32x4 wv = waT[s * 16 + i];
            acc[0] = fmaf(sel, wv[0], acc[0]);
            acc[1] = fmaf(sel, wv[1], acc[1]);
            acc[2] = fmaf(sel, wv[2], acc[2]);
            acc[3] = fmaf(sel, wv[3], acc[3]);
        }
    }
    sc[tid] = acc;
    __syncthreads();
    float bd = bact;
    for (int d = 1; d < 256; d <<= 1) {
        f32x4 cv = sc[tid];
        f32x4 pv = { 0.f, 0.f, 0.f, 0.f };
        if (tid >= d) pv = sc[tid - d];
        __syncthreads();
        cv[0] = fmaf(bd, pv[0], cv[0]);
        cv[1] = fmaf(bd, pv[1], cv[1]);
        cv[2] = fmaf(bd, pv[2], cv[2]);
        cv[3] = fmaf(bd, pv[3], cv[3]);
        sc[tid] = cv;
        __syncthreads();
        bd *= bd;
    }
    f32x4 res = sc[tid];
    *(f32x4*)(out + (size_t)tid * 512 + b * 4) = res;
}

extern "C" void kernel_launch(void* const* d_in, const int* in_sizes, int n_in,
                              void* d_out, int out_size, void* d_ws, size_t ws_size,
                              hipStream_t stream)
{
    const float* batch    = (const float*)d_in[0];
    const float* W1       = (const float*)d_in[1];
    const float* b1       = (const float*)d_in[2];
    const float* beta1    = (const float*)d_in[3];
    const float* thr1     = (const float*)d_in[4];
    const float* W2       = (const float*)d_in[5];
    const float* b2       = (const float*)d_in[6];
    const float* beta2    = (const float*)d_in[7];
    const float* thr2     = (const float*)d_in[8];
    const float* Wa       = (const float*)d_in[9];
    const float* ba       = (const float*)d_in[10];
    const float* beta_act = (const float*)d_in[11];
    const float* inp_min  = (const float*)d_in[12];
    const float* inp_max  = (const float*)d_in[13];
    float* out            = (float*)d_out;

    char* ws = (char*)d_ws;
    unsigned short* W2hi    = (unsigned short*)ws;                          // 512 KiB
    unsigned short* W2lo    = (unsigned short*)(ws + (512u << 10));         // 512 KiB
    unsigned short* W1rows  = (unsigned short*)(ws + (1u << 20));           // 64 KiB
    float*          b1s     = (float*)(ws + (1u << 20) + (64u << 10));      // 2 KiB
    unsigned short* Xf      = (unsigned short*)(ws + (2u << 20));           // 8 MiB
    unsigned short* spkbits = (unsigned short*)(ws + (10u << 20));          // 2 MiB

    hipLaunchKernelGGL(k_prep, dim3(770), dim3(256), 0, stream,
                       W2, W1, b1, thr1, inp_min, inp_max, batch,
                       W2hi, W2lo, W1rows, b1s, Xf);
    hipLaunchKernelGGL(k_main, dim3(256), dim3(1024), 0, stream,
                       Xf, W2hi, W2lo, W1rows, b1s, beta1, b2, beta2, thr2, spkbits);
    hipLaunchKernelGGL(k_act, dim3(128), dim3(256), 0, stream, spkbits, Wa, ba, beta_act, out);
}